// Round 3
// 440.301 us; speedup vs baseline: 1.1393x; 1.1393x over previous
//
#include <hip/hip_runtime.h>
#include <hip/hip_bf16.h>

// MessagePassing: out = (A / rowsum|A|) @ X @ W + b
//   A [8192,8192] f32, X [8192,512] f32, W [512,256] f32, b [256] f32 -> out [8192,256] f32
//
// R5 (2nd resubmit; two infra failures, source audited clean 3x):
// algebraic reassociation. (A_n @ X) @ W == A_n @ (X @ W).
// Y = X@W is [8192,256] (2.1 GF, trivial). Big GEMM becomes A @ Y:
//   - half the K-iterations per block (32 vs 64) at unchanged per-iter staging
//     bytes -> halves the VMEM-issue-bound cadence (R4: 3.34 us/iter, ~6 B/cyc/CU)
//   - ks = blockIdx&7 -> each XCD owns one 1024-wide K-slice: A read exactly
//     once device-wide (1 GB logical -> 256 MB), YT slice (0.5 MB) L2-resident
//   - Sacc (16 MB) + memset + gemm2 + X-transpose + 16.7M-atomic tail all deleted.
//     Split-K partials are plain stores into P[8][8192][256] f32; tiny finalize
//     does (sum_s P)/rowsum + bias. Atomic fallback if ws too small.
//
// Pipeline:
//   k0: transpose_cvt  W -> WT bf16 [256][512]
//   k1: gemm_xw        Y = X @ W            (f32 out, gemm2-style 64x128 tile)
//   k2: transpose_cvt  Y -> YT bf16 [256][8192]
//   k3: gemm_ay        P[ks] = A_slice @ Y_slice, Rp[ks] = partial rowsum|A|
//       grid 256 = 32 rb x 8 ks, BM=256 BN=256 BK=32, 1024 thr, 16 waves 4x4
//   k4: finalize       Out = (sum_s P[s]) / max(sum_s Rp[s],eps) + bias
// ws: WT 256K | YT 4M | Y 8M | P 64M | Rp 256K  = 76.5 MiB (atomic path: 20.3 MiB)

typedef __attribute__((ext_vector_type(8))) __bf16 bf16x8;
typedef __attribute__((ext_vector_type(4))) float f32x4;

#define AS1 __attribute__((address_space(1)))
#define AS3 __attribute__((address_space(3)))

__device__ __forceinline__ void async_load16(const void* g, void* l) {
  __builtin_amdgcn_global_load_lds((const AS1 void*)g, (AS3 void*)l, 16, 0, 0);
}

// ---------------- kernel: 64x64 tiled transpose + f32->bf16 ----------------
__global__ __launch_bounds__(256) void transpose_cvt_kernel(
    const float* __restrict__ src, __hip_bfloat16* __restrict__ dst, int R, int C) {
  __shared__ float tile[64][65];
  const int t = threadIdx.x;
  const int nrb = R >> 6;
  const int rb = blockIdx.x % nrb, cb = blockIdx.x / nrb;
  const int r0 = rb * 64, c0 = cb * 64;
  const int lr = t >> 4, lc4 = (t & 15) * 4;
#pragma unroll
  for (int p = 0; p < 4; ++p) {
    const int r = p * 16 + lr;
    const f32x4 v = *(const f32x4*)(src + (size_t)(r0 + r) * C + c0 + lc4);
    tile[r][lc4 + 0] = v[0]; tile[r][lc4 + 1] = v[1];
    tile[r][lc4 + 2] = v[2]; tile[r][lc4 + 3] = v[3];
  }
  __syncthreads();
#pragma unroll
  for (int i = 0; i < 16; ++i) {
    const int idx = i * 256 + t;
    const int n = idx >> 6, k = idx & 63;
    dst[(size_t)(c0 + n) * R + r0 + k] = __float2bfloat16(tile[k][n]);
  }
}

// ---------------- kernel: Y = X @ W  (small GEMM, gemm2 structure) ----------------
// BM=64, BN=128, BK=64, 256 threads (4 waves 2x2), wave-tile 32x64, 8 K-iters.
__global__ __launch_bounds__(256) void gemm_xw_kernel(
    const float* __restrict__ X,            // [8192][512] f32
    const __hip_bfloat16* __restrict__ WT,  // [256][512]
    float* __restrict__ Y)                  // [8192][256] f32
{
  __shared__ char smem[49152];
  char* Sbase = smem;            // [2][64 rows][128 B], chunk P = c ^ (row&7)
  char* Wbase = smem + 16384;    // [2][128 n  ][128 B], chunk P = c ^ (n&7)

  const int t = threadIdx.x;
  const int wave = t >> 6, lane = t & 63;
  const int quad = lane >> 4, l16 = lane & 15;

  const int b = blockIdx.x;
  const int xcd = b & 7, s = b >> 3;
  const int rb = xcd * 16 + (s >> 1), cb = s & 1;
  const int r0 = rb * 64, c0 = cb * 128;

  const int wm = wave & 1, wn = wave >> 1;

  f32x4 acc[2][4] = {};

  const int am = t >> 2;
  const int kq = t & 3;
  const float* sp = X + (size_t)(r0 + am) * 512 + kq * 16;
  const int sw0 = am * 128 + (((kq * 2 + 0) ^ (am & 7)) * 16);
  const int sw1 = am * 128 + (((kq * 2 + 1) ^ (am & 7)) * 16);

  f32x4 sreg[4];
#pragma unroll
  for (int i = 0; i < 4; ++i) sreg[i] = *(const f32x4*)(sp + i * 4);

  // W prologue (kt=0 -> buf0)
#pragma unroll
  for (int i = 0; i < 4; ++i) {
    const int slot = i * 256 + t;
    const int n = slot >> 3;
    const int G = (slot & 7) ^ (n & 7);
    async_load16(WT + (size_t)(c0 + n) * 512 + G * 8, Wbase + slot * 16);
  }

  int cur = 0;
#pragma unroll 2
  for (int kt = 0; kt < 8; ++kt) {
    {  // stage X(kt): cvt, 2 swizzled ds_write_b128
      char* sw = Sbase + cur * 8192;
      bf16x8 v0, v1;
#pragma unroll
      for (int j = 0; j < 4; ++j) {
        v0[j]     = (__bf16)(sreg[0][j]);
        v0[j + 4] = (__bf16)(sreg[1][j]);
        v1[j]     = (__bf16)(sreg[2][j]);
        v1[j + 4] = (__bf16)(sreg[3][j]);
      }
      *(bf16x8*)(sw + sw0) = v0;
      *(bf16x8*)(sw + sw1) = v1;
    }
    __syncthreads();

    if (kt < 7) {  // prefetch kt+1
      const float* spk = sp + (kt + 1) * 64;
#pragma unroll
      for (int i = 0; i < 4; ++i) sreg[i] = *(const f32x4*)(spk + i * 4);
#pragma unroll
      for (int i = 0; i < 4; ++i) {
        const int slot = i * 256 + t;
        const int n = slot >> 3;
        const int G = (slot & 7) ^ (n & 7);
        async_load16(WT + (size_t)(c0 + n) * 512 + (kt + 1) * 64 + G * 8,
                     Wbase + (cur ^ 1) * 16384 + slot * 16);
      }
    }

    {  // compute: 12 ds_read_b128 + 16 MFMA per wave
      const char* sb = Sbase + cur * 8192;
      const char* wb = Wbase + cur * 16384;
      bf16x8 af[2][2];
#pragma unroll
      for (int rt = 0; rt < 2; ++rt) {
        const int row = wm * 32 + rt * 16 + l16;
#pragma unroll
        for (int kb = 0; kb < 2; ++kb) {
          const int ch = (kb * 4 + quad) ^ (row & 7);
          af[rt][kb] = *(const bf16x8*)(sb + row * 128 + ch * 16);
        }
      }
#pragma unroll
      for (int ct = 0; ct < 4; ++ct) {
        const int n = wn * 64 + ct * 16 + l16;
#pragma unroll
        for (int kb = 0; kb < 2; ++kb) {
          const int ch = (kb * 4 + quad) ^ (n & 7);
          const bf16x8 bfr = *(const bf16x8*)(wb + n * 128 + ch * 16);
#pragma unroll
          for (int rt = 0; rt < 2; ++rt)
            acc[rt][ct] = __builtin_amdgcn_mfma_f32_16x16x32_bf16(
                af[rt][kb], bfr, acc[rt][ct], 0, 0, 0);
        }
      }
    }
    cur ^= 1;
  }

#pragma unroll
  for (int rt = 0; rt < 2; ++rt) {
#pragma unroll
    for (int r = 0; r < 4; ++r) {
      const int row_l = wm * 32 + rt * 16 + quad * 4 + r;
#pragma unroll
      for (int ct = 0; ct < 4; ++ct) {
        const int col_l = wn * 64 + ct * 16 + l16;
        Y[(size_t)(r0 + row_l) * 256 + c0 + col_l] = acc[rt][ct][r];
      }
    }
  }
}

// ---------------- kernel: split-K  P[ks] = A_slice @ Y_slice ----------------
// BM=256, BN=256 (full width), BK=32, Kslice=1024 -> 32 iters.
// grid 256 = 32 rb x 8 ks; ks = blockIdx&7 = XCD id -> A read once device-wide,
// YT slice (256 x 1024 x 2B = 0.5 MB) L2-resident per XCD.
// LDS row-pair swizzle identical to the verified R4 gemm1 layout.
__global__ __launch_bounds__(1024, 4) void gemm_ay_kernel(
    const float* __restrict__ A,            // [8192][8192]
    const __hip_bfloat16* __restrict__ YT,  // [256][8192]
    float* __restrict__ Pb,                 // [8][8192][256] f32 (plain) or [8192][256] (atomic)
    float* __restrict__ Rb,                 // [8][8192] (plain) or [8192] (atomic, zeroed)
    int atomic_flag)
{
  __shared__ char smem[65536];
  char* Abase = smem;             // [2][128 row-pairs][128 B]
  char* Ybase = smem + 32768;     // [2][128 col-pairs][128 B]
  float* rsmem = (float*)Ybase;   // aliases Ybuf[0]; compute(31) uses buf1

  const int t = threadIdx.x;
  const int wave = t >> 6, lane = t & 63;
  const int quad = lane >> 4, l16 = lane & 15;

  const int b = blockIdx.x;
  const int ks = b & 7;                     // XCD id
  const int rb = b >> 3;                    // 0..31
  const int r0 = rb * 256;
  const int k0 = ks * 1024;

  const int wm = wave & 3, wn = wave >> 2;

  f32x4 acc[4][4] = {};
  float rs = 0.0f;

  // A staging: thread -> row am = t>>2 (256 rows), 16B-chunk kc = t&3
  const int am = t >> 2;
  const int kc = t & 3;
  const float* ap = A + (size_t)(r0 + am) * 8192 + k0 + kc * 8;
  const int aw_off = (am >> 1) * 128 + (((kc + 4 * (am & 1)) ^ ((am >> 1) & 7)) * 16);

  f32x4 areg[2];
  areg[0] = *(const f32x4*)(ap);
  areg[1] = *(const f32x4*)(ap + 4);

  // Y prologue (kt=0 -> buf0): 1024 slots of 16 B, source-address inverse swizzle
  {
    const int q = t >> 3;
    const int u = (t & 7) ^ (q & 7);
    const int n = 2 * q + (u >> 2), g = u & 3;
    async_load16(YT + (size_t)n * 8192 + k0 + g * 8, Ybase + t * 16);
  }

  int cur = 0;
#pragma unroll 2
  for (int kt = 0; kt < 32; ++kt) {
    {  // stage A(kt): rowsum + cvt + one swizzled ds_write_b128
      const f32x4 e = areg[0], o = areg[1];
      rs += fabsf(e[0]) + fabsf(e[1]) + fabsf(e[2]) + fabsf(e[3]) +
            fabsf(o[0]) + fabsf(o[1]) + fabsf(o[2]) + fabsf(o[3]);
      bf16x8 v;
      v[0] = (__bf16)e[0]; v[1] = (__bf16)e[1]; v[2] = (__bf16)e[2]; v[3] = (__bf16)e[3];
      v[4] = (__bf16)o[0]; v[5] = (__bf16)o[1]; v[6] = (__bf16)o[2]; v[7] = (__bf16)o[3];
      *(bf16x8*)(Abase + cur * 16384 + aw_off) = v;
    }
    __syncthreads();

    if (kt < 31) {  // prefetch kt+1
      const float* apk = ap + (kt + 1) * 32;
      areg[0] = *(const f32x4*)(apk);
      areg[1] = *(const f32x4*)(apk + 4);
      const int q = t >> 3;
      const int u = (t & 7) ^ (q & 7);
      const int n = 2 * q + (u >> 2), g = u & 3;
      async_load16(YT + (size_t)n * 8192 + k0 + (kt + 1) * 32 + g * 8,
                   Ybase + (cur ^ 1) * 16384 + t * 16);
    }

    {  // compute: 8 ds_read_b128 + 16 MFMA per wave
      const char* ab = Abase + cur * 16384;
      const char* xb = Ybase + cur * 16384;
      bf16x8 af[4];
#pragma unroll
      for (int rt = 0; rt < 4; ++rt) {
        const int row = wm * 64 + rt * 16 + l16;
        const int off = (row >> 1) * 128 + (((quad + 4 * (row & 1)) ^ ((row >> 1) & 7)) * 16);
        af[rt] = *(const bf16x8*)(ab + off);
      }
#pragma unroll
      for (int ct = 0; ct < 4; ++ct) {
        const int n = wn * 64 + ct * 16 + l16;
        const int off = (n >> 1) * 128 + (((quad + 4 * (n & 1)) ^ ((n >> 1) & 7)) * 16);
        const bf16x8 bfr = *(const bf16x8*)(xb + off);
#pragma unroll
        for (int rt = 0; rt < 4; ++rt)
          acc[rt][ct] = __builtin_amdgcn_mfma_f32_16x16x32_bf16(
              af[rt], bfr, acc[rt][ct], 0, 0, 0);
      }
    }
    cur ^= 1;
  }

  // epilogue: rowsum reduce (4 threads per row) + partial store / atomic
  rsmem[t] = rs;  // Ybuf0 region; compute(31) used buf1
  __syncthreads();
  if (t < 256) {
    const float v = rsmem[4 * t] + rsmem[4 * t + 1] + rsmem[4 * t + 2] + rsmem[4 * t + 3];
    if (atomic_flag) atomicAdd(&Rb[r0 + t], v);
    else             Rb[(size_t)ks * 8192 + r0 + t] = v;
  }

  if (atomic_flag) {
#pragma unroll
    for (int rt = 0; rt < 4; ++rt)
#pragma unroll
      for (int r = 0; r < 4; ++r) {
        const int row_l = wm * 64 + rt * 16 + quad * 4 + r;  // C/D: row=(lane>>4)*4+reg
#pragma unroll
        for (int ct = 0; ct < 4; ++ct) {
          const int col_l = wn * 64 + ct * 16 + l16;         // C/D: col=lane&15
          atomicAdd(&Pb[(size_t)(r0 + row_l) * 256 + col_l], acc[rt][ct][r]);
        }
      }
  } else {
    float* dst = Pb + (size_t)ks * (8192 * 256);
#pragma unroll
    for (int rt = 0; rt < 4; ++rt)
#pragma unroll
      for (int r = 0; r < 4; ++r) {
        const int row_l = wm * 64 + rt * 16 + quad * 4 + r;
#pragma unroll
        for (int ct = 0; ct < 4; ++ct) {
          const int col_l = wn * 64 + ct * 16 + l16;
          dst[(size_t)(r0 + row_l) * 256 + col_l] = acc[rt][ct][r];
        }
      }
  }
}

// ---------------- kernel: Out = (sum_s P[s]) / max(sum_s Rp[s], eps) + bias ----------------
__global__ __launch_bounds__(256) void finalize_kernel(
    const float* __restrict__ Pb,   // [S][8192][256]
    const float* __restrict__ Rb,   // [S][8192]
    const float* __restrict__ bias, // [256]
    float* __restrict__ Out,        // [8192][256]
    int S)
{
  const int idx = blockIdx.x * 256 + threadIdx.x;
  const int i  = idx >> 6;          // row
  const int j4 = (idx & 63) << 2;   // col (x4)
  float rsum = 0.0f;
  for (int s = 0; s < S; ++s) rsum += Rb[(size_t)s * 8192 + i];
  const float inv = 1.0f / fmaxf(rsum, 1e-12f);
  f32x4 a = {};
  for (int s = 0; s < S; ++s) {
    const f32x4 p = *(const f32x4*)(Pb + (size_t)s * (8192 * 256) + (size_t)i * 256 + j4);
    a += p;
  }
  const f32x4 bv = *(const f32x4*)(bias + j4);
  const f32x4 o = a * inv + bv;
  *(f32x4*)(Out + (size_t)i * 256 + j4) = o;
}

extern "C" void kernel_launch(void* const* d_in, const int* in_sizes, int n_in,
                              void* d_out, int out_size, void* d_ws, size_t ws_size,
                              hipStream_t stream) {
  const float* A    = (const float*)d_in[0];
  const float* Xf   = (const float*)d_in[1];
  const float* Wf   = (const float*)d_in[2];
  const float* bias = (const float*)d_in[3];
  float* Out = (float*)d_out;

  char* ws = (char*)d_ws;
  __hip_bfloat16* WT = (__hip_bfloat16*)ws;                 // [256][512]   256 KiB
  __hip_bfloat16* YT = (__hip_bfloat16*)(ws + 262144);      // [256][8192]  4 MiB
  float*          Y  = (float*)(ws + 4456448);              // [8192][256]  8 MiB
  char*         tail = ws + 12845056;

  const size_t need_plain = 12845056ull + 67108864ull + 262144ull;  // +P(64M)+Rp(256K)
  float* Pb; float* Rb; int atomic_flag; int S;
  if (ws_size >= need_plain) {
    Pb = (float*)tail;                     // [8][8192][256] 64 MiB
    Rb = (float*)(tail + 67108864);        // [8][8192]      256 KiB
    atomic_flag = 0; S = 8;
  } else {
    Pb = (float*)tail;                     // [8192][256]    8 MiB
    Rb = (float*)(tail + 8388608);         // [8192]         32 KiB
    atomic_flag = 1; S = 1;
    hipMemsetAsync(tail, 0, 8388608 + 32768, stream);
  }

  transpose_cvt_kernel<<<32, 256, 0, stream>>>(Wf, WT, 512, 256);
  gemm_xw_kernel<<<256, 256, 0, stream>>>(Xf, WT, Y);
  transpose_cvt_kernel<<<512, 256, 0, stream>>>(Y, YT, 8192, 256);
  gemm_ay_kernel<<<256, 1024, 0, stream>>>(A, YT, Pb, Rb, atomic_flag);
  finalize_kernel<<<2048, 256, 0, stream>>>(Pb, Rb, bias, Out, S);
}

// Round 4
// 435.147 us; speedup vs baseline: 1.1528x; 1.0118x over previous
//
#include <hip/hip_runtime.h>
#include <hip/hip_bf16.h>

// MessagePassing: out = (A / rowsum|A|) @ X @ W + b
//   A [8192,8192] f32, X [8192,512] f32, W [512,256] f32, b [256] f32 -> out [8192,256] f32
//
// R6: MLP (memory-level-parallelism) round. R5 profile showed the 1-GiB harness
// poison fill runs at 6.7 TB/s while gemm kernels idle at ~2 TB/s with all pipes
// <13% -> the limiter is outstanding-request starvation (1 lockstep block/CU,
// vmcnt(0) drain at every barrier), NOT a per-CU byte pin.
//   gemm_ay v2: BM=128, 512 thr (8 waves 2x4), 48 KiB LDS -> 512 blocks
//   = 2 independent blocks/CU; one block's compute covers the other's drain.
//   Y tile duplication (2x/CU) is L2-served, doesn't touch HBM.
// Also fuse Y-transpose into gemm_xw (LDS-transpose epilogue writes YT bf16
// directly): one fewer dispatch, -16 MB Y f32 round trip.
//
// Pipeline:
//   k0: transpose_cvt  W -> WT bf16 [256][512]
//   k1: gemm_xw        YT = (X @ W)^T bf16 [256][8192]   (fused transpose epi)
//   k2: gemm_ay        P[ks] = A_slice @ Y_slice, Rp[ks] = partial rowsum|A|
//       grid 512 = 64 rb x 8 ks, BM=128 BN=256 BK=32, 512 thr, 2 blocks/CU
//   k3: finalize       Out = (sum_s P[s]) / max(sum_s Rp[s],eps) + bias
// ws: WT 256K | YT 4M | P 64M | Rp 256K = 68.5 MiB (atomic fallback: 12.9 MiB)

typedef __attribute__((ext_vector_type(8))) __bf16 bf16x8;
typedef __attribute__((ext_vector_type(4))) float f32x4;

#define AS1 __attribute__((address_space(1)))
#define AS3 __attribute__((address_space(3)))

__device__ __forceinline__ void async_load16(const void* g, void* l) {
  __builtin_amdgcn_global_load_lds((const AS1 void*)g, (AS3 void*)l, 16, 0, 0);
}

// ---------------- kernel: 64x64 tiled transpose + f32->bf16 ----------------
__global__ __launch_bounds__(256) void transpose_cvt_kernel(
    const float* __restrict__ src, __hip_bfloat16* __restrict__ dst, int R, int C) {
  __shared__ float tile[64][65];
  const int t = threadIdx.x;
  const int nrb = R >> 6;
  const int rb = blockIdx.x % nrb, cb = blockIdx.x / nrb;
  const int r0 = rb * 64, c0 = cb * 64;
  const int lr = t >> 4, lc4 = (t & 15) * 4;
#pragma unroll
  for (int p = 0; p < 4; ++p) {
    const int r = p * 16 + lr;
    const f32x4 v = *(const f32x4*)(src + (size_t)(r0 + r) * C + c0 + lc4);
    tile[r][lc4 + 0] = v[0]; tile[r][lc4 + 1] = v[1];
    tile[r][lc4 + 2] = v[2]; tile[r][lc4 + 3] = v[3];
  }
  __syncthreads();
#pragma unroll
  for (int i = 0; i < 16; ++i) {
    const int idx = i * 256 + t;
    const int n = idx >> 6, k = idx & 63;
    dst[(size_t)(c0 + n) * R + r0 + k] = __float2bfloat16(tile[k][n]);
  }
}

// ---------------- kernel: YT = (X @ W)^T  (small GEMM + fused transpose) ----------------
// BM=64, BN=128, BK=64, 256 threads (4 waves 2x2), wave-tile 32x64, 8 K-iters.
// Epilogue: acc -> LDS [128 col][64 row] bf16 -> coalesced YT write.
__global__ __launch_bounds__(256) void gemm_xw_kernel(
    const float* __restrict__ X,            // [8192][512] f32
    const __hip_bfloat16* __restrict__ WT,  // [256][512]
    __hip_bfloat16* __restrict__ YT)        // [256][8192] bf16
{
  __shared__ char smem[49152];
  char* Sbase = smem;            // [2][64 rows][128 B], chunk P = c ^ (row&7)
  char* Wbase = smem + 16384;    // [2][128 n  ][128 B], chunk P = c ^ (n&7)

  const int t = threadIdx.x;
  const int wave = t >> 6, lane = t & 63;
  const int quad = lane >> 4, l16 = lane & 15;

  const int b = blockIdx.x;
  const int xcd = b & 7, s = b >> 3;
  const int rb = xcd * 16 + (s >> 1), cb = s & 1;
  const int r0 = rb * 64, c0 = cb * 128;

  const int wm = wave & 1, wn = wave >> 1;

  f32x4 acc[2][4] = {};

  const int am = t >> 2;
  const int kq = t & 3;
  const float* sp = X + (size_t)(r0 + am) * 512 + kq * 16;
  const int sw0 = am * 128 + (((kq * 2 + 0) ^ (am & 7)) * 16);
  const int sw1 = am * 128 + (((kq * 2 + 1) ^ (am & 7)) * 16);

  f32x4 sreg[4];
#pragma unroll
  for (int i = 0; i < 4; ++i) sreg[i] = *(const f32x4*)(sp + i * 4);

  // W prologue (kt=0 -> buf0)
#pragma unroll
  for (int i = 0; i < 4; ++i) {
    const int slot = i * 256 + t;
    const int n = slot >> 3;
    const int G = (slot & 7) ^ (n & 7);
    async_load16(WT + (size_t)(c0 + n) * 512 + G * 8, Wbase + slot * 16);
  }

  int cur = 0;
#pragma unroll 2
  for (int kt = 0; kt < 8; ++kt) {
    {  // stage X(kt): cvt, 2 swizzled ds_write_b128
      char* sw = Sbase + cur * 8192;
      bf16x8 v0, v1;
#pragma unroll
      for (int j = 0; j < 4; ++j) {
        v0[j]     = (__bf16)(sreg[0][j]);
        v0[j + 4] = (__bf16)(sreg[1][j]);
        v1[j]     = (__bf16)(sreg[2][j]);
        v1[j + 4] = (__bf16)(sreg[3][j]);
      }
      *(bf16x8*)(sw + sw0) = v0;
      *(bf16x8*)(sw + sw1) = v1;
    }
    __syncthreads();

    if (kt < 7) {  // prefetch kt+1
      const float* spk = sp + (kt + 1) * 64;
#pragma unroll
      for (int i = 0; i < 4; ++i) sreg[i] = *(const f32x4*)(spk + i * 4);
#pragma unroll
      for (int i = 0; i < 4; ++i) {
        const int slot = i * 256 + t;
        const int n = slot >> 3;
        const int G = (slot & 7) ^ (n & 7);
        async_load16(WT + (size_t)(c0 + n) * 512 + (kt + 1) * 64 + G * 8,
                     Wbase + (cur ^ 1) * 16384 + slot * 16);
      }
    }

    {  // compute: 12 ds_read_b128 + 16 MFMA per wave
      const char* sb = Sbase + cur * 8192;
      const char* wb = Wbase + cur * 16384;
      bf16x8 af[2][2];
#pragma unroll
      for (int rt = 0; rt < 2; ++rt) {
        const int row = wm * 32 + rt * 16 + l16;
#pragma unroll
        for (int kb = 0; kb < 2; ++kb) {
          const int ch = (kb * 4 + quad) ^ (row & 7);
          af[rt][kb] = *(const bf16x8*)(sb + row * 128 + ch * 16);
        }
      }
#pragma unroll
      for (int ct = 0; ct < 4; ++ct) {
        const int n = wn * 64 + ct * 16 + l16;
#pragma unroll
        for (int kb = 0; kb < 2; ++kb) {
          const int ch = (kb * 4 + quad) ^ (n & 7);
          const bf16x8 bfr = *(const bf16x8*)(wb + n * 128 + ch * 16);
#pragma unroll
          for (int rt = 0; rt < 2; ++rt)
            acc[rt][ct] = __builtin_amdgcn_mfma_f32_16x16x32_bf16(
                af[rt][kb], bfr, acc[rt][ct], 0, 0, 0);
        }
      }
    }
    cur ^= 1;
  }

  // fused transpose epilogue: acc -> Tr[128 col][64 row] bf16 -> coalesced YT
  __syncthreads();  // all compute(7) reads done before Tr overwrites smem
  __hip_bfloat16* Tr = (__hip_bfloat16*)smem;  // 16 KiB
#pragma unroll
  for (int rt = 0; rt < 2; ++rt) {
#pragma unroll
    for (int r = 0; r < 4; ++r) {
      const int row_l = wm * 32 + rt * 16 + quad * 4 + r;   // C/D: row=(lane>>4)*4+reg
#pragma unroll
      for (int ct = 0; ct < 4; ++ct) {
        const int col_l = wn * 64 + ct * 16 + l16;          // C/D: col=lane&15
        Tr[col_l * 64 + row_l] = __float2bfloat16(acc[rt][ct][r]);
      }
    }
  }
  __syncthreads();
  // 128 cols x 64 rows x 2 B = 16 KiB = 1024 chunks of 16 B; 4 chunks/thread
#pragma unroll
  for (int i = 0; i < 4; ++i) {
    const int c = i * 256 + t;
    const int col = c >> 3, part = c & 7;
    *(f32x4*)(YT + (size_t)(c0 + col) * 8192 + r0 + part * 8) =
        *(const f32x4*)(Tr + col * 64 + part * 8);
  }
}

// ---------------- kernel: split-K  P[ks] = A_slice @ Y_slice ----------------
// BM=128, BN=256, BK=32, Kslice=1024 -> 32 iters. 512 thr (8 waves 2x4),
// 48 KiB LDS -> 2 blocks/CU for cross-block latency hiding (MLP).
// grid 512 = 64 rb x 8 ks; ks = blockIdx&7 = XCD id -> A read once device-wide,
// YT slice (0.5 MB) L2-resident per XCD. Same verified row-pair LDS swizzle.
__global__ __launch_bounds__(512, 4) void gemm_ay_kernel(
    const float* __restrict__ A,            // [8192][8192]
    const __hip_bfloat16* __restrict__ YT,  // [256][8192]
    float* __restrict__ Pb,                 // [8][8192][256] f32 (plain) or [8192][256] (atomic)
    float* __restrict__ Rb,                 // [8][8192] (plain) or [8192] (atomic, zeroed)
    int atomic_flag)
{
  __shared__ char smem[49152];
  char* Abase = smem;             // [2][64 row-pairs][128 B]  (2 x 8 KiB)
  char* Ybase = smem + 16384;     // [2][128 col-pairs][128 B] (2 x 16 KiB)
  float* rsmem = (float*)Ybase;   // aliases Ybuf[0]; compute(31) uses buf1

  const int t = threadIdx.x;
  const int wave = t >> 6, lane = t & 63;
  const int quad = lane >> 4, l16 = lane & 15;

  const int b = blockIdx.x;
  const int ks = b & 7;                     // XCD id
  const int rb = b >> 3;                    // 0..63
  const int r0 = rb * 128;
  const int k0 = ks * 1024;

  const int wm = wave & 1, wn = wave >> 1;  // 2 x 4 wave grid, wave-tile 64x64

  f32x4 acc[4][4] = {};
  float rs = 0.0f;

  // A staging: thread -> row am = t>>2 (128 rows), 16B-bf16-chunk kc = t&3
  const int am = t >> 2;
  const int kc = t & 3;
  const float* ap = A + (size_t)(r0 + am) * 8192 + k0 + kc * 8;
  const int aw_off = (am >> 1) * 128 + (((kc + 4 * (am & 1)) ^ ((am >> 1) & 7)) * 16);

  f32x4 areg[2];
  areg[0] = *(const f32x4*)(ap);
  areg[1] = *(const f32x4*)(ap + 4);

  // Y prologue (kt=0 -> buf0): 1024 slots of 16 B, 2 per thread,
  // source-address inverse swizzle
#pragma unroll
  for (int i = 0; i < 2; ++i) {
    const int s = i * 512 + t;
    const int q = s >> 3;
    const int u = (s & 7) ^ (q & 7);
    const int n = 2 * q + (u >> 2), g = u & 3;
    async_load16(YT + (size_t)n * 8192 + k0 + g * 8, Ybase + s * 16);
  }

  int cur = 0;
#pragma unroll 2
  for (int kt = 0; kt < 32; ++kt) {
    {  // stage A(kt): rowsum + cvt + one swizzled ds_write_b128
      const f32x4 e = areg[0], o = areg[1];
      rs += fabsf(e[0]) + fabsf(e[1]) + fabsf(e[2]) + fabsf(e[3]) +
            fabsf(o[0]) + fabsf(o[1]) + fabsf(o[2]) + fabsf(o[3]);
      bf16x8 v;
      v[0] = (__bf16)e[0]; v[1] = (__bf16)e[1]; v[2] = (__bf16)e[2]; v[3] = (__bf16)e[3];
      v[4] = (__bf16)o[0]; v[5] = (__bf16)o[1]; v[6] = (__bf16)o[2]; v[7] = (__bf16)o[3];
      *(bf16x8*)(Abase + cur * 8192 + aw_off) = v;
    }
    __syncthreads();

    if (kt < 31) {  // prefetch kt+1: A (HBM, issue first) then Y (L2)
      const float* apk = ap + (kt + 1) * 32;
      areg[0] = *(const f32x4*)(apk);
      areg[1] = *(const f32x4*)(apk + 4);
#pragma unroll
      for (int i = 0; i < 2; ++i) {
        const int s = i * 512 + t;
        const int q = s >> 3;
        const int u = (s & 7) ^ (q & 7);
        const int n = 2 * q + (u >> 2), g = u & 3;
        async_load16(YT + (size_t)n * 8192 + k0 + (kt + 1) * 32 + g * 8,
                     Ybase + (cur ^ 1) * 16384 + s * 16);
      }
    }

    {  // compute: 8 ds_read_b128 + 16 MFMA per wave
      const char* ab = Abase + cur * 8192;
      const char* xb = Ybase + cur * 16384;
      bf16x8 af[4];
#pragma unroll
      for (int rt = 0; rt < 4; ++rt) {
        const int row = wm * 64 + rt * 16 + l16;
        const int off = (row >> 1) * 128 + (((quad + 4 * (row & 1)) ^ ((row >> 1) & 7)) * 16);
        af[rt] = *(const bf16x8*)(ab + off);
      }
#pragma unroll
      for (int ct = 0; ct < 4; ++ct) {
        const int n = wn * 64 + ct * 16 + l16;
        const int off = (n >> 1) * 128 + (((quad + 4 * (n & 1)) ^ ((n >> 1) & 7)) * 16);
        const bf16x8 bfr = *(const bf16x8*)(xb + off);
#pragma unroll
        for (int rt = 0; rt < 4; ++rt)
          acc[rt][ct] = __builtin_amdgcn_mfma_f32_16x16x32_bf16(
              af[rt], bfr, acc[rt][ct], 0, 0, 0);
      }
    }
    cur ^= 1;
  }

  // epilogue: rowsum reduce (4 threads per row) + partial store / atomic
  rsmem[t] = rs;  // Ybuf0 region; compute(31) used buf1 (disjoint)
  __syncthreads();
  if (t < 128) {
    const float v = rsmem[4 * t] + rsmem[4 * t + 1] + rsmem[4 * t + 2] + rsmem[4 * t + 3];
    if (atomic_flag) atomicAdd(&Rb[r0 + t], v);
    else             Rb[(size_t)ks * 8192 + r0 + t] = v;
  }

  if (atomic_flag) {
#pragma unroll
    for (int rt = 0; rt < 4; ++rt)
#pragma unroll
      for (int r = 0; r < 4; ++r) {
        const int row_l = wm * 64 + rt * 16 + quad * 4 + r;  // C/D: row=(lane>>4)*4+reg
#pragma unroll
        for (int ct = 0; ct < 4; ++ct) {
          const int col_l = wn * 64 + ct * 16 + l16;         // C/D: col=lane&15
          atomicAdd(&Pb[(size_t)(r0 + row_l) * 256 + col_l], acc[rt][ct][r]);
        }
      }
  } else {
    float* dst = Pb + (size_t)ks * (8192 * 256);
#pragma unroll
    for (int rt = 0; rt < 4; ++rt)
#pragma unroll
      for (int r = 0; r < 4; ++r) {
        const int row_l = wm * 64 + rt * 16 + quad * 4 + r;
#pragma unroll
        for (int ct = 0; ct < 4; ++ct) {
          const int col_l = wn * 64 + ct * 16 + l16;
          dst[(size_t)(r0 + row_l) * 256 + col_l] = acc[rt][ct][r];
        }
      }
  }
}

// ---------------- kernel: Out = (sum_s P[s]) / max(sum_s Rp[s], eps) + bias ----------------
__global__ __launch_bounds__(256) void finalize_kernel(
    const float* __restrict__ Pb,   // [S][8192][256]
    const float* __restrict__ Rb,   // [S][8192]
    const float* __restrict__ bias, // [256]
    float* __restrict__ Out,        // [8192][256]
    int S)
{
  const int idx = blockIdx.x * 256 + threadIdx.x;
  const int i  = idx >> 6;          // row
  const int j4 = (idx & 63) << 2;   // col (x4)
  float rsum = 0.0f;
  for (int s = 0; s < S; ++s) rsum += Rb[(size_t)s * 8192 + i];
  const float inv = 1.0f / fmaxf(rsum, 1e-12f);
  f32x4 a = {};
  for (int s = 0; s < S; ++s) {
    const f32x4 p = *(const f32x4*)(Pb + (size_t)s * (8192 * 256) + (size_t)i * 256 + j4);
    a += p;
  }
  const f32x4 bv = *(const f32x4*)(bias + j4);
  const f32x4 o = a * inv + bv;
  *(f32x4*)(Out + (size_t)i * 256 + j4) = o;
}

extern "C" void kernel_launch(void* const* d_in, const int* in_sizes, int n_in,
                              void* d_out, int out_size, void* d_ws, size_t ws_size,
                              hipStream_t stream) {
  const float* A    = (const float*)d_in[0];
  const float* Xf   = (const float*)d_in[1];
  const float* Wf   = (const float*)d_in[2];
  const float* bias = (const float*)d_in[3];
  float* Out = (float*)d_out;

  char* ws = (char*)d_ws;
  __hip_bfloat16* WT = (__hip_bfloat16*)ws;                 // [256][512]   256 KiB
  __hip_bfloat16* YT = (__hip_bfloat16*)(ws + 262144);      // [256][8192]  4 MiB
  char*         tail = ws + 4456448;

  const size_t need_plain = 4456448ull + 67108864ull + 262144ull;  // +P(64M)+Rp(256K)
  float* Pb; float* Rb; int atomic_flag; int S;
  if (ws_size >= need_plain) {
    Pb = (float*)tail;                     // [8][8192][256] 64 MiB
    Rb = (float*)(tail + 67108864);        // [8][8192]      256 KiB
    atomic_flag = 0; S = 8;
  } else {
    Pb = (float*)tail;                     // [8192][256]    8 MiB
    Rb = (float*)(tail + 8388608);         // [8192]         32 KiB
    atomic_flag = 1; S = 1;
    hipMemsetAsync(tail, 0, 8388608 + 32768, stream);
  }

  transpose_cvt_kernel<<<32, 256, 0, stream>>>(Wf, WT, 512, 256);
  gemm_xw_kernel<<<256, 256, 0, stream>>>(Xf, WT, YT);
  gemm_ay_kernel<<<512, 512, 0, stream>>>(A, YT, Pb, Rb, atomic_flag);
  finalize_kernel<<<2048, 256, 0, stream>>>(Pb, Rb, bias, Out, S);
}

// Round 5
// 418.809 us; speedup vs baseline: 1.1977x; 1.0390x over previous
//
#include <hip/hip_runtime.h>
#include <hip/hip_bf16.h>

// MessagePassing: out = (A / rowsum|A|) @ X @ W + b
//   A [8192,8192] f32, X [8192,512] f32, W [512,256] f32, b [256] f32 -> out [8192,256] f32
//
// R7: burst-length round. R6 post-mortem: 2 blocks/CU changed nothing -> the
// ~2 TB/s wall on A is NOT request-count starvation. Every prior version read
// A as BMx128B column slices at 32 KB power-of-2 stride; the 6.6 TB/s poison
// fill is linear. Bet: short-burst/channel inefficiency. Fix: BK=128 -> 512 B
// contiguous per row per stage, full-K per block:
//   gemm_ay v3: BM=64 BN=128 BK=128, K=8192 (64 iters), grid 256 = 2cb x 128rb
//   (b = cb*128+rb -> cb-pair shares XCD -> A read once, pair L2-hits),
//   512 thr (8 waves 2x4, wave-tile 32x32), 96 KiB LDS, depth-2 A prefetch,
//   16-chunk XOR swizzle (2 lanes/bank = conflict-free).
//   Full-K => rowsum complete in-block => normalize+bias fused epilogue writes
//   Out directly. P buffer (64MB wr + 72MB rd), finalize, atomics: DELETED.
// HBM budget: A 256 MB + Out 8 MB + Y 4 MB + X 16 MB ~= 285 MB.
//
// Pipeline:
//   k0: transpose_cvt  W -> WT bf16 [256][512]
//   k1: gemm_xw        YT = (X @ W)^T bf16 [256][8192]   (fused transpose epi)
//   k2: gemm_ay        Out = (A/rowsum|A|) @ Y + bias    (direct, no split-K)
// ws: WT 256K | YT 4M = 4.25 MiB

typedef __attribute__((ext_vector_type(8))) __bf16 bf16x8;
typedef __attribute__((ext_vector_type(4))) float f32x4;

#define AS1 __attribute__((address_space(1)))
#define AS3 __attribute__((address_space(3)))

__device__ __forceinline__ void async_load16(const void* g, void* l) {
  __builtin_amdgcn_global_load_lds((const AS1 void*)g, (AS3 void*)l, 16, 0, 0);
}

// ---------------- kernel: 64x64 tiled transpose + f32->bf16 ----------------
__global__ __launch_bounds__(256) void transpose_cvt_kernel(
    const float* __restrict__ src, __hip_bfloat16* __restrict__ dst, int R, int C) {
  __shared__ float tile[64][65];
  const int t = threadIdx.x;
  const int nrb = R >> 6;
  const int rb = blockIdx.x % nrb, cb = blockIdx.x / nrb;
  const int r0 = rb * 64, c0 = cb * 64;
  const int lr = t >> 4, lc4 = (t & 15) * 4;
#pragma unroll
  for (int p = 0; p < 4; ++p) {
    const int r = p * 16 + lr;
    const f32x4 v = *(const f32x4*)(src + (size_t)(r0 + r) * C + c0 + lc4);
    tile[r][lc4 + 0] = v[0]; tile[r][lc4 + 1] = v[1];
    tile[r][lc4 + 2] = v[2]; tile[r][lc4 + 3] = v[3];
  }
  __syncthreads();
#pragma unroll
  for (int i = 0; i < 16; ++i) {
    const int idx = i * 256 + t;
    const int n = idx >> 6, k = idx & 63;
    dst[(size_t)(c0 + n) * R + r0 + k] = __float2bfloat16(tile[k][n]);
  }
}

// ---------------- kernel: YT = (X @ W)^T  (small GEMM + fused transpose) ----------------
// BM=64, BN=128, BK=64, 256 threads (4 waves 2x2), wave-tile 32x64, 8 K-iters.
// Epilogue: acc -> LDS [128 col][64 row] bf16 -> coalesced YT write.
__global__ __launch_bounds__(256) void gemm_xw_kernel(
    const float* __restrict__ X,            // [8192][512] f32
    const __hip_bfloat16* __restrict__ WT,  // [256][512]
    __hip_bfloat16* __restrict__ YT)        // [256][8192] bf16
{
  __shared__ char smem[49152];
  char* Sbase = smem;            // [2][64 rows][128 B], chunk P = c ^ (row&7)
  char* Wbase = smem + 16384;    // [2][128 n  ][128 B], chunk P = c ^ (n&7)

  const int t = threadIdx.x;
  const int wave = t >> 6, lane = t & 63;
  const int quad = lane >> 4, l16 = lane & 15;

  const int b = blockIdx.x;
  const int xcd = b & 7, s = b >> 3;
  const int rb = xcd * 16 + (s >> 1), cb = s & 1;
  const int r0 = rb * 64, c0 = cb * 128;

  const int wm = wave & 1, wn = wave >> 1;

  f32x4 acc[2][4] = {};

  const int am = t >> 2;
  const int kq = t & 3;
  const float* sp = X + (size_t)(r0 + am) * 512 + kq * 16;
  const int sw0 = am * 128 + (((kq * 2 + 0) ^ (am & 7)) * 16);
  const int sw1 = am * 128 + (((kq * 2 + 1) ^ (am & 7)) * 16);

  f32x4 sreg[4];
#pragma unroll
  for (int i = 0; i < 4; ++i) sreg[i] = *(const f32x4*)(sp + i * 4);

  // W prologue (kt=0 -> buf0)
#pragma unroll
  for (int i = 0; i < 4; ++i) {
    const int slot = i * 256 + t;
    const int n = slot >> 3;
    const int G = (slot & 7) ^ (n & 7);
    async_load16(WT + (size_t)(c0 + n) * 512 + G * 8, Wbase + slot * 16);
  }

  int cur = 0;
#pragma unroll 2
  for (int kt = 0; kt < 8; ++kt) {
    {  // stage X(kt): cvt, 2 swizzled ds_write_b128
      char* sw = Sbase + cur * 8192;
      bf16x8 v0, v1;
#pragma unroll
      for (int j = 0; j < 4; ++j) {
        v0[j]     = (__bf16)(sreg[0][j]);
        v0[j + 4] = (__bf16)(sreg[1][j]);
        v1[j]     = (__bf16)(sreg[2][j]);
        v1[j + 4] = (__bf16)(sreg[3][j]);
      }
      *(bf16x8*)(sw + sw0) = v0;
      *(bf16x8*)(sw + sw1) = v1;
    }
    __syncthreads();

    if (kt < 7) {  // prefetch kt+1
      const float* spk = sp + (kt + 1) * 64;
#pragma unroll
      for (int i = 0; i < 4; ++i) sreg[i] = *(const f32x4*)(spk + i * 4);
#pragma unroll
      for (int i = 0; i < 4; ++i) {
        const int slot = i * 256 + t;
        const int n = slot >> 3;
        const int G = (slot & 7) ^ (n & 7);
        async_load16(WT + (size_t)(c0 + n) * 512 + (kt + 1) * 64 + G * 8,
                     Wbase + (cur ^ 1) * 16384 + slot * 16);
      }
    }

    {  // compute: 12 ds_read_b128 + 16 MFMA per wave
      const char* sb = Sbase + cur * 8192;
      const char* wb = Wbase + cur * 16384;
      bf16x8 af[2][2];
#pragma unroll
      for (int rt = 0; rt < 2; ++rt) {
        const int row = wm * 32 + rt * 16 + l16;
#pragma unroll
        for (int kb = 0; kb < 2; ++kb) {
          const int ch = (kb * 4 + quad) ^ (row & 7);
          af[rt][kb] = *(const bf16x8*)(sb + row * 128 + ch * 16);
        }
      }
#pragma unroll
      for (int ct = 0; ct < 4; ++ct) {
        const int n = wn * 64 + ct * 16 + l16;
#pragma unroll
        for (int kb = 0; kb < 2; ++kb) {
          const int ch = (kb * 4 + quad) ^ (n & 7);
          const bf16x8 bfr = *(const bf16x8*)(wb + n * 128 + ch * 16);
#pragma unroll
          for (int rt = 0; rt < 2; ++rt)
            acc[rt][ct] = __builtin_amdgcn_mfma_f32_16x16x32_bf16(
                af[rt][kb], bfr, acc[rt][ct], 0, 0, 0);
        }
      }
    }
    cur ^= 1;
  }

  // fused transpose epilogue: acc -> Tr[128 col][64 row] bf16 -> coalesced YT
  __syncthreads();  // all compute(7) reads done before Tr overwrites smem
  __hip_bfloat16* Tr = (__hip_bfloat16*)smem;  // 16 KiB
#pragma unroll
  for (int rt = 0; rt < 2; ++rt) {
#pragma unroll
    for (int r = 0; r < 4; ++r) {
      const int row_l = wm * 32 + rt * 16 + quad * 4 + r;   // C/D: row=(lane>>4)*4+reg
#pragma unroll
      for (int ct = 0; ct < 4; ++ct) {
        const int col_l = wn * 64 + ct * 16 + l16;          // C/D: col=lane&15
        Tr[col_l * 64 + row_l] = __float2bfloat16(acc[rt][ct][r]);
      }
    }
  }
  __syncthreads();
  // 128 cols x 64 rows x 2 B = 16 KiB = 1024 chunks of 16 B; 4 chunks/thread
#pragma unroll
  for (int i = 0; i < 4; ++i) {
    const int c = i * 256 + t;
    const int col = c >> 3, part = c & 7;
    *(f32x4*)(YT + (size_t)(c0 + col) * 8192 + r0 + part * 8) =
        *(const f32x4*)(Tr + col * 64 + part * 8);
  }
}

// ---------------- kernel: Out = (A / rowsum|A|) @ Y + bias  (full-K, direct) ----------------
// BM=64, BN=128, BK=128, 64 K-iters. 512 thr (8 waves 2x4, wave-tile 32x32).
// LDS 96 KiB: A [2][64 rows][256 B], Y [2][128 n][256 B], chunk XOR-16 swizzle.
// A staged through regs (rowsum+cvt), 512 B contiguous per row per stage,
// depth-2 prefetch; Y via global_load_lds with source-side inverse swizzle.
// b = cb*128+rb: cb-pair lands on one XCD -> A fetched once, pair L2-hits.
__global__ __launch_bounds__(512, 2) void gemm_ay_kernel(
    const float* __restrict__ A,            // [8192][8192]
    const __hip_bfloat16* __restrict__ YT,  // [256][8192]
    const float* __restrict__ bias,         // [256]
    float* __restrict__ Out)                // [8192][256]
{
  __shared__ char smem[98304];
  char* Abase = smem;            // [2][64 rows][256 B]  2 x 16 KiB
  char* Ybase = smem + 32768;    // [2][128 n  ][256 B]  2 x 32 KiB

  const int t = threadIdx.x;
  const int wave = t >> 6, lane = t & 63;
  const int quad = lane >> 4, l16 = lane & 15;

  const int b = blockIdx.x;
  const int cb = b >> 7, rb = b & 127;
  const int r0 = rb * 64, c0 = cb * 128;

  const int wm = wave & 1, wn = wave >> 1;   // 2 x 4 waves, wave-tile 32x32

  f32x4 acc[2][2] = {};
  float rs = 0.0f;

  // A staging: thread -> row am = t>>3 (64 rows), 16-float group kc = t&7
  const int am = t >> 3, kc = t & 7;
  const float* ap = A + (size_t)(r0 + am) * 8192 + kc * 16;
  // swizzled write offsets for the two 16-B bf16 chunks (chunks 2kc, 2kc+1)
  const int aw0 = am * 256 + (((2 * kc + 0) ^ (am & 15)) * 16);
  const int aw1 = am * 256 + (((2 * kc + 1) ^ (am & 15)) * 16);

  f32x4 areg[2][4];
  // prologue: A(0) -> areg[0], A(1) -> areg[1], Y(0) -> Ybuf0
#pragma unroll
  for (int i = 0; i < 4; ++i) areg[0][i] = *(const f32x4*)(ap + i * 4);
#pragma unroll
  for (int i = 0; i < 4; ++i) areg[1][i] = *(const f32x4*)(ap + 128 + i * 4);
#pragma unroll
  for (int i = 0; i < 4; ++i) {
    const int s = i * 512 + t;
    const int n = s >> 4;
    const int lg = (s & 15) ^ (n & 15);
    async_load16(YT + (size_t)(c0 + n) * 8192 + lg * 8, Ybase + s * 16);
  }

  int cur = 0;
#pragma unroll 2
  for (int kt = 0; kt < 64; ++kt) {
    {  // stage A(kt): rowsum + cvt + 2 swizzled ds_write_b128
      const int p = kt & 1;
      const f32x4 a0 = areg[p][0], a1 = areg[p][1], a2 = areg[p][2], a3 = areg[p][3];
      rs += fabsf(a0[0]) + fabsf(a0[1]) + fabsf(a0[2]) + fabsf(a0[3]) +
            fabsf(a1[0]) + fabsf(a1[1]) + fabsf(a1[2]) + fabsf(a1[3]) +
            fabsf(a2[0]) + fabsf(a2[1]) + fabsf(a2[2]) + fabsf(a2[3]) +
            fabsf(a3[0]) + fabsf(a3[1]) + fabsf(a3[2]) + fabsf(a3[3]);
      bf16x8 v0, v1;
#pragma unroll
      for (int j = 0; j < 4; ++j) {
        v0[j] = (__bf16)a0[j]; v0[j + 4] = (__bf16)a1[j];
        v1[j] = (__bf16)a2[j]; v1[j + 4] = (__bf16)a3[j];
      }
      char* aw = Abase + cur * 16384;
      *(bf16x8*)(aw + aw0) = v0;
      *(bf16x8*)(aw + aw1) = v1;
    }
    __syncthreads();

    if (kt < 62) {  // depth-2 A prefetch: A(kt+2) -> areg[kt&1] (just consumed)
      const float* apk = ap + (size_t)(kt + 2) * 128;
#pragma unroll
      for (int i = 0; i < 4; ++i) areg[kt & 1][i] = *(const f32x4*)(apk + i * 4);
    }
    if (kt < 63) {  // Y(kt+1) -> Ybuf^1 (L2-resident stream)
#pragma unroll
      for (int i = 0; i < 4; ++i) {
        const int s = i * 512 + t;
        const int n = s >> 4;
        const int lg = (s & 15) ^ (n & 15);
        async_load16(YT + (size_t)(c0 + n) * 8192 + (kt + 1) * 128 + lg * 8,
                     Ybase + (cur ^ 1) * 32768 + s * 16);
      }
    }

    {  // compute: 16 ds_read_b128 + 16 MFMA per wave
      const char* ab = Abase + cur * 16384;
      const char* yb = Ybase + cur * 32768;
      bf16x8 af[2][4];
#pragma unroll
      for (int rt = 0; rt < 2; ++rt) {
        const int row = wm * 32 + rt * 16 + l16;
#pragma unroll
        for (int kb = 0; kb < 4; ++kb) {
          const int ch = (kb * 4 + quad) ^ (row & 15);
          af[rt][kb] = *(const bf16x8*)(ab + row * 256 + ch * 16);
        }
      }
#pragma unroll
      for (int ct = 0; ct < 2; ++ct) {
        const int n = wn * 32 + ct * 16 + l16;
#pragma unroll
        for (int kb = 0; kb < 4; ++kb) {
          const int ch = (kb * 4 + quad) ^ (n & 15);
          const bf16x8 bfr = *(const bf16x8*)(yb + n * 256 + ch * 16);
#pragma unroll
          for (int rt = 0; rt < 2; ++rt)
            acc[rt][ct] = __builtin_amdgcn_mfma_f32_16x16x32_bf16(
                af[rt][kb], bfr, acc[rt][ct], 0, 0, 0);
        }
      }
    }
    cur ^= 1;
  }

  // epilogue: rowsum reduce (8 threads/row) -> inv, then normalize+bias -> Out.
  // compute(63) read buf1; Abuf0 is free for the reduction scratch.
  float* rsmem = (float*)Abase;           // 512 partials
  float* rinv  = (float*)(Abase + 2048);  // 64 per-row inverses
  rsmem[t] = rs;
  __syncthreads();
  if (t < 64) {
    float v = 0.0f;
#pragma unroll
    for (int j = 0; j < 8; ++j) v += rsmem[t * 8 + j];
    rinv[t] = 1.0f / fmaxf(v, 1e-12f);
  }
  __syncthreads();
#pragma unroll
  for (int rt = 0; rt < 2; ++rt) {
#pragma unroll
    for (int r = 0; r < 4; ++r) {
      const int row_l = wm * 32 + rt * 16 + quad * 4 + r;  // C/D: row=(lane>>4)*4+reg
      const float inv = rinv[row_l];
#pragma unroll
      for (int ct = 0; ct < 2; ++ct) {
        const int col_l = wn * 32 + ct * 16 + l16;         // C/D: col=lane&15
        Out[(size_t)(r0 + row_l) * 256 + c0 + col_l] =
            acc[rt][ct][r] * inv + bias[c0 + col_l];
      }
    }
  }
}

extern "C" void kernel_launch(void* const* d_in, const int* in_sizes, int n_in,
                              void* d_out, int out_size, void* d_ws, size_t ws_size,
                              hipStream_t stream) {
  const float* A    = (const float*)d_in[0];
  const float* Xf   = (const float*)d_in[1];
  const float* Wf   = (const float*)d_in[2];
  const float* bias = (const float*)d_in[3];
  float* Out = (float*)d_out;

  char* ws = (char*)d_ws;
  __hip_bfloat16* WT = (__hip_bfloat16*)ws;                 // [256][512]   256 KiB
  __hip_bfloat16* YT = (__hip_bfloat16*)(ws + 262144);      // [256][8192]  4 MiB

  transpose_cvt_kernel<<<32, 256, 0, stream>>>(Wf, WT, 512, 256);
  gemm_xw_kernel<<<256, 256, 0, stream>>>(Xf, WT, YT);
  gemm_ay_kernel<<<256, 512, 0, stream>>>(A, YT, bias, Out);
}

// Round 6
// 408.837 us; speedup vs baseline: 1.2269x; 1.0244x over previous
//
#include <hip/hip_runtime.h>
#include <hip/hip_bf16.h>

// MessagePassing: out = (A / rowsum|A|) @ X @ W + b
//   A [8192,8192] f32, X [8192,512] f32, W [512,256] f32, b [256] f32 -> out [8192,256] f32
//
// R8: channel-decamping round. R6 (2 blocks/CU) and R7 (BK=128 bursts) both
// left gemm_ay at ~2.2 TB/s on A -> the wall is structure-invariant. The one
// invariant: all 256 blocks march K-synchronized, so the whole device reads
// the SAME 512-B column window of A (32 KB pow-2 row stride) at any instant
// -> camps on a fraction of HBM channels. The 6.7 TB/s poison fill is linear.
// Fix: per-block K-phase rotation (accumulation is K-order-invariant):
//   kk = (kt + phase) & 63, phase = (rb*37) & 63
// Blocks now cover 64 different column windows simultaneously -> all channels
// busy. Everything else (tiles, LDS, schedule, barriers) identical to R7.
// cb-pair (b, b+128) shares rb -> same phase -> A still read once via L2.
//
// Pipeline:
//   k0: transpose_cvt  W -> WT bf16 [256][512]
//   k1: gemm_xw        YT = (X @ W)^T bf16 [256][8192]   (fused transpose epi)
//   k2: gemm_ay        Out = (A/rowsum|A|) @ Y + bias    (full-K, direct)
// ws: WT 256K | YT 4M = 4.25 MiB

typedef __attribute__((ext_vector_type(8))) __bf16 bf16x8;
typedef __attribute__((ext_vector_type(4))) float f32x4;

#define AS1 __attribute__((address_space(1)))
#define AS3 __attribute__((address_space(3)))

__device__ __forceinline__ void async_load16(const void* g, void* l) {
  __builtin_amdgcn_global_load_lds((const AS1 void*)g, (AS3 void*)l, 16, 0, 0);
}

// ---------------- kernel: 64x64 tiled transpose + f32->bf16 ----------------
__global__ __launch_bounds__(256) void transpose_cvt_kernel(
    const float* __restrict__ src, __hip_bfloat16* __restrict__ dst, int R, int C) {
  __shared__ float tile[64][65];
  const int t = threadIdx.x;
  const int nrb = R >> 6;
  const int rb = blockIdx.x % nrb, cb = blockIdx.x / nrb;
  const int r0 = rb * 64, c0 = cb * 64;
  const int lr = t >> 4, lc4 = (t & 15) * 4;
#pragma unroll
  for (int p = 0; p < 4; ++p) {
    const int r = p * 16 + lr;
    const f32x4 v = *(const f32x4*)(src + (size_t)(r0 + r) * C + c0 + lc4);
    tile[r][lc4 + 0] = v[0]; tile[r][lc4 + 1] = v[1];
    tile[r][lc4 + 2] = v[2]; tile[r][lc4 + 3] = v[3];
  }
  __syncthreads();
#pragma unroll
  for (int i = 0; i < 16; ++i) {
    const int idx = i * 256 + t;
    const int n = idx >> 6, k = idx & 63;
    dst[(size_t)(c0 + n) * R + r0 + k] = __float2bfloat16(tile[k][n]);
  }
}

// ---------------- kernel: YT = (X @ W)^T  (small GEMM + fused transpose) ----------------
// BM=64, BN=128, BK=64, 256 threads (4 waves 2x2), wave-tile 32x64, 8 K-iters.
// Epilogue: acc -> LDS [128 col][64 row] bf16 -> coalesced YT write.
__global__ __launch_bounds__(256) void gemm_xw_kernel(
    const float* __restrict__ X,            // [8192][512] f32
    const __hip_bfloat16* __restrict__ WT,  // [256][512]
    __hip_bfloat16* __restrict__ YT)        // [256][8192] bf16
{
  __shared__ char smem[49152];
  char* Sbase = smem;            // [2][64 rows][128 B], chunk P = c ^ (row&7)
  char* Wbase = smem + 16384;    // [2][128 n  ][128 B], chunk P = c ^ (n&7)

  const int t = threadIdx.x;
  const int wave = t >> 6, lane = t & 63;
  const int quad = lane >> 4, l16 = lane & 15;

  const int b = blockIdx.x;
  const int xcd = b & 7, s = b >> 3;
  const int rb = xcd * 16 + (s >> 1), cb = s & 1;
  const int r0 = rb * 64, c0 = cb * 128;

  const int wm = wave & 1, wn = wave >> 1;

  f32x4 acc[2][4] = {};

  const int am = t >> 2;
  const int kq = t & 3;
  const float* sp = X + (size_t)(r0 + am) * 512 + kq * 16;
  const int sw0 = am * 128 + (((kq * 2 + 0) ^ (am & 7)) * 16);
  const int sw1 = am * 128 + (((kq * 2 + 1) ^ (am & 7)) * 16);

  f32x4 sreg[4];
#pragma unroll
  for (int i = 0; i < 4; ++i) sreg[i] = *(const f32x4*)(sp + i * 4);

  // W prologue (kt=0 -> buf0)
#pragma unroll
  for (int i = 0; i < 4; ++i) {
    const int slot = i * 256 + t;
    const int n = slot >> 3;
    const int G = (slot & 7) ^ (n & 7);
    async_load16(WT + (size_t)(c0 + n) * 512 + G * 8, Wbase + slot * 16);
  }

  int cur = 0;
#pragma unroll 2
  for (int kt = 0; kt < 8; ++kt) {
    {  // stage X(kt): cvt, 2 swizzled ds_write_b128
      char* sw = Sbase + cur * 8192;
      bf16x8 v0, v1;
#pragma unroll
      for (int j = 0; j < 4; ++j) {
        v0[j]     = (__bf16)(sreg[0][j]);
        v0[j + 4] = (__bf16)(sreg[1][j]);
        v1[j]     = (__bf16)(sreg[2][j]);
        v1[j + 4] = (__bf16)(sreg[3][j]);
      }
      *(bf16x8*)(sw + sw0) = v0;
      *(bf16x8*)(sw + sw1) = v1;
    }
    __syncthreads();

    if (kt < 7) {  // prefetch kt+1
      const float* spk = sp + (kt + 1) * 64;
#pragma unroll
      for (int i = 0; i < 4; ++i) sreg[i] = *(const f32x4*)(spk + i * 4);
#pragma unroll
      for (int i = 0; i < 4; ++i) {
        const int slot = i * 256 + t;
        const int n = slot >> 3;
        const int G = (slot & 7) ^ (n & 7);
        async_load16(WT + (size_t)(c0 + n) * 512 + (kt + 1) * 64 + G * 8,
                     Wbase + (cur ^ 1) * 16384 + slot * 16);
      }
    }

    {  // compute: 12 ds_read_b128 + 16 MFMA per wave
      const char* sb = Sbase + cur * 8192;
      const char* wb = Wbase + cur * 16384;
      bf16x8 af[2][2];
#pragma unroll
      for (int rt = 0; rt < 2; ++rt) {
        const int row = wm * 32 + rt * 16 + l16;
#pragma unroll
        for (int kb = 0; kb < 2; ++kb) {
          const int ch = (kb * 4 + quad) ^ (row & 7);
          af[rt][kb] = *(const bf16x8*)(sb + row * 128 + ch * 16);
        }
      }
#pragma unroll
      for (int ct = 0; ct < 4; ++ct) {
        const int n = wn * 64 + ct * 16 + l16;
#pragma unroll
        for (int kb = 0; kb < 2; ++kb) {
          const int ch = (kb * 4 + quad) ^ (n & 7);
          const bf16x8 bfr = *(const bf16x8*)(wb + n * 128 + ch * 16);
#pragma unroll
          for (int rt = 0; rt < 2; ++rt)
            acc[rt][ct] = __builtin_amdgcn_mfma_f32_16x16x32_bf16(
                af[rt][kb], bfr, acc[rt][ct], 0, 0, 0);
        }
      }
    }
    cur ^= 1;
  }

  // fused transpose epilogue: acc -> Tr[128 col][64 row] bf16 -> coalesced YT
  __syncthreads();  // all compute(7) reads done before Tr overwrites smem
  __hip_bfloat16* Tr = (__hip_bfloat16*)smem;  // 16 KiB
#pragma unroll
  for (int rt = 0; rt < 2; ++rt) {
#pragma unroll
    for (int r = 0; r < 4; ++r) {
      const int row_l = wm * 32 + rt * 16 + quad * 4 + r;   // C/D: row=(lane>>4)*4+reg
#pragma unroll
      for (int ct = 0; ct < 4; ++ct) {
        const int col_l = wn * 64 + ct * 16 + l16;          // C/D: col=lane&15
        Tr[col_l * 64 + row_l] = __float2bfloat16(acc[rt][ct][r]);
      }
    }
  }
  __syncthreads();
  // 128 cols x 64 rows x 2 B = 16 KiB = 1024 chunks of 16 B; 4 chunks/thread
#pragma unroll
  for (int i = 0; i < 4; ++i) {
    const int c = i * 256 + t;
    const int col = c >> 3, part = c & 7;
    *(f32x4*)(YT + (size_t)(c0 + col) * 8192 + r0 + part * 8) =
        *(const f32x4*)(Tr + col * 64 + part * 8);
  }
}

// ---------------- kernel: Out = (A / rowsum|A|) @ Y + bias  (full-K, direct) ----------------
// BM=64, BN=128, BK=128, 64 K-iters processed in PER-BLOCK ROTATED ORDER:
//   kk = (kt + phase) & 63, phase = (rb*37) & 63  (K-accumulation is
//   order-invariant) -> blocks cover 64 distinct 512-B column windows of A
//   simultaneously instead of all camping on one -> full HBM channel spread.
// 512 thr (8 waves 2x4, wave-tile 32x32). LDS 96 KiB: A [2][64][256B],
// Y [2][128][256B], chunk XOR-16 swizzle. Depth-2 A reg prefetch; Y via
// global_load_lds (L2-resident). cb-pair shares rb/phase -> A read once.
__global__ __launch_bounds__(512, 2) void gemm_ay_kernel(
    const float* __restrict__ A,            // [8192][8192]
    const __hip_bfloat16* __restrict__ YT,  // [256][8192]
    const float* __restrict__ bias,         // [256]
    float* __restrict__ Out)                // [8192][256]
{
  __shared__ char smem[98304];
  char* Abase = smem;            // [2][64 rows][256 B]  2 x 16 KiB
  char* Ybase = smem + 32768;    // [2][128 n  ][256 B]  2 x 32 KiB

  const int t = threadIdx.x;
  const int wave = t >> 6, lane = t & 63;
  const int quad = lane >> 4, l16 = lane & 15;

  const int b = blockIdx.x;
  const int cb = b >> 7, rb = b & 127;
  const int r0 = rb * 64, c0 = cb * 128;
  const int phase = (rb * 37) & 63;          // per-block K rotation

  const int wm = wave & 1, wn = wave >> 1;   // 2 x 4 waves, wave-tile 32x32

  f32x4 acc[2][2] = {};
  float rs = 0.0f;

  // A staging: thread -> row am = t>>3 (64 rows), 16-float group kc = t&7
  const int am = t >> 3, kc = t & 7;
  const float* ap = A + (size_t)(r0 + am) * 8192 + kc * 16;
  // swizzled write offsets for the two 16-B bf16 chunks (chunks 2kc, 2kc+1)
  const int aw0 = am * 256 + (((2 * kc + 0) ^ (am & 15)) * 16);
  const int aw1 = am * 256 + (((2 * kc + 1) ^ (am & 15)) * 16);

  f32x4 areg[2][4];
  // prologue: A(kk=phase) -> areg[0], A(kk=phase+1) -> areg[1], Y(phase) -> Ybuf0
  {
    const int kk0 = phase, kk1 = (phase + 1) & 63;
#pragma unroll
    for (int i = 0; i < 4; ++i) areg[0][i] = *(const f32x4*)(ap + kk0 * 128 + i * 4);
#pragma unroll
    for (int i = 0; i < 4; ++i) areg[1][i] = *(const f32x4*)(ap + kk1 * 128 + i * 4);
#pragma unroll
    for (int i = 0; i < 4; ++i) {
      const int s = i * 512 + t;
      const int n = s >> 4;
      const int lg = (s & 15) ^ (n & 15);
      async_load16(YT + (size_t)(c0 + n) * 8192 + kk0 * 128 + lg * 8, Ybase + s * 16);
    }
  }

  int cur = 0;
#pragma unroll 2
  for (int kt = 0; kt < 64; ++kt) {
    {  // stage A(kt): rowsum + cvt + 2 swizzled ds_write_b128
      const int p = kt & 1;
      const f32x4 a0 = areg[p][0], a1 = areg[p][1], a2 = areg[p][2], a3 = areg[p][3];
      rs += fabsf(a0[0]) + fabsf(a0[1]) + fabsf(a0[2]) + fabsf(a0[3]) +
            fabsf(a1[0]) + fabsf(a1[1]) + fabsf(a1[2]) + fabsf(a1[3]) +
            fabsf(a2[0]) + fabsf(a2[1]) + fabsf(a2[2]) + fabsf(a2[3]) +
            fabsf(a3[0]) + fabsf(a3[1]) + fabsf(a3[2]) + fabsf(a3[3]);
      bf16x8 v0, v1;
#pragma unroll
      for (int j = 0; j < 4; ++j) {
        v0[j] = (__bf16)a0[j]; v0[j + 4] = (__bf16)a1[j];
        v1[j] = (__bf16)a2[j]; v1[j + 4] = (__bf16)a3[j];
      }
      char* aw = Abase + cur * 16384;
      *(bf16x8*)(aw + aw0) = v0;
      *(bf16x8*)(aw + aw1) = v1;
    }
    __syncthreads();

    if (kt < 62) {  // depth-2 A prefetch: column (kt+2+phase)&63 -> areg[kt&1]
      const int kk2 = (kt + 2 + phase) & 63;
      const float* apk = ap + (size_t)kk2 * 128;
#pragma unroll
      for (int i = 0; i < 4; ++i) areg[kt & 1][i] = *(const f32x4*)(apk + i * 4);
    }
    if (kt < 63) {  // Y column (kt+1+phase)&63 -> Ybuf^1 (L2-resident stream)
      const int kk1 = (kt + 1 + phase) & 63;
#pragma unroll
      for (int i = 0; i < 4; ++i) {
        const int s = i * 512 + t;
        const int n = s >> 4;
        const int lg = (s & 15) ^ (n & 15);
        async_load16(YT + (size_t)(c0 + n) * 8192 + kk1 * 128 + lg * 8,
                     Ybase + (cur ^ 1) * 32768 + s * 16);
      }
    }

    {  // compute: 16 ds_read_b128 + 16 MFMA per wave
      const char* ab = Abase + cur * 16384;
      const char* yb = Ybase + cur * 32768;
      bf16x8 af[2][4];
#pragma unroll
      for (int rt = 0; rt < 2; ++rt) {
        const int row = wm * 32 + rt * 16 + l16;
#pragma unroll
        for (int kb = 0; kb < 4; ++kb) {
          const int ch = (kb * 4 + quad) ^ (row & 15);
          af[rt][kb] = *(const bf16x8*)(ab + row * 256 + ch * 16);
        }
      }
#pragma unroll
      for (int ct = 0; ct < 2; ++ct) {
        const int n = wn * 32 + ct * 16 + l16;
#pragma unroll
        for (int kb = 0; kb < 4; ++kb) {
          const int ch = (kb * 4 + quad) ^ (n & 15);
          const bf16x8 bfr = *(const bf16x8*)(yb + n * 256 + ch * 16);
#pragma unroll
          for (int rt = 0; rt < 2; ++rt)
            acc[rt][ct] = __builtin_amdgcn_mfma_f32_16x16x32_bf16(
                af[rt][kb], bfr, acc[rt][ct], 0, 0, 0);
        }
      }
    }
    cur ^= 1;
  }

  // epilogue: rowsum reduce (8 threads/row) -> inv, then normalize+bias -> Out.
  // compute(63) read buf1; Abuf0 is free for the reduction scratch.
  float* rsmem = (float*)Abase;           // 512 partials
  float* rinv  = (float*)(Abase + 2048);  // 64 per-row inverses
  rsmem[t] = rs;
  __syncthreads();
  if (t < 64) {
    float v = 0.0f;
#pragma unroll
    for (int j = 0; j < 8; ++j) v += rsmem[t * 8 + j];
    rinv[t] = 1.0f / fmaxf(v, 1e-12f);
  }
  __syncthreads();
#pragma unroll
  for (int rt = 0; rt < 2; ++rt) {
#pragma unroll
    for (int r = 0; r < 4; ++r) {
      const int row_l = wm * 32 + rt * 16 + quad * 4 + r;  // C/D: row=(lane>>4)*4+reg
      const float inv = rinv[row_l];
#pragma unroll
      for (int ct = 0; ct < 2; ++ct) {
        const int col_l = wn * 32 + ct * 16 + l16;         // C/D: col=lane&15
        Out[(size_t)(r0 + row_l) * 256 + c0 + col_l] =
            acc[rt][ct][r] * inv + bias[c0 + col_l];
      }
    }
  }
}

extern "C" void kernel_launch(void* const* d_in, const int* in_sizes, int n_in,
                              void* d_out, int out_size, void* d_ws, size_t ws_size,
                              hipStream_t stream) {
  const float* A    = (const float*)d_in[0];
  const float* Xf   = (const float*)d_in[1];
  const float* Wf   = (const float*)d_in[2];
  const float* bias = (const float*)d_in[3];
  float* Out = (float*)d_out;

  char* ws = (char*)d_ws;
  __hip_bfloat16* WT = (__hip_bfloat16*)ws;                 // [256][512]   256 KiB
  __hip_bfloat16* YT = (__hip_bfloat16*)(ws + 262144);      // [256][8192]  4 MiB

  transpose_cvt_kernel<<<32, 256, 0, stream>>>(Wf, WT, 512, 256);
  gemm_xw_kernel<<<256, 256, 0, stream>>>(Xf, WT, YT);
  gemm_ay_kernel<<<256, 512, 0, stream>>>(A, YT, bias, Out);
}

// Round 8
// 399.252 us; speedup vs baseline: 1.2564x; 1.0240x over previous
//
#include <hip/hip_runtime.h>
#include <hip/hip_bf16.h>

// MessagePassing: out = (A / rowsum|A|) @ X @ W + b
//   A [8192,8192] f32, X [8192,512] f32, W [512,256] f32, b [256] f32 -> out [8192,256] f32
//
// R10 = R9 (split-K staged-bytes round) with the race-suspect epilogue fixed.
// R9 passed first-call verification then DIVERGED post-timing (1.9e-2): a real
// nondeterminism. Only unproven structure was the rowsum epilogue aliasing
// rsmem onto Abuf0 while compute(31) drains Abuf1/Ybuf1 reads. R10 removes
// epilogue LDS entirely: each row's 4 partials live in 4 ADJACENT LANES of one
// wave -> two __shfl_xor + one store. No alias, no barrier, race-proof.
//
// Staged-bytes theory (unchanged from R9): R4-R8 all land at ~12-14 B/cyc/CU
// of issued VMEM bytes (~4500 cyc per 64-KB iter). One-block-per-tile forces
// BM*BN=8192 (R8 = constrained optimum, 1.02 GB staged). Split-K relaxes it:
// BM=128 BN=256 Ks=2048 (grid 256 = 64 rb x 4 ks): A issued ONCE (256 MB),
// Y 256 MB, per-iter bytes unchanged but 32 iters instead of 64 -> ~2x main
// loop under both candidate models (byte-limited and cycle-floor).
//
// Pipeline:
//   k0: transpose_cvt  W -> WT bf16 [256][512]
//   k1: gemm_xw        YT = (X @ W)^T bf16 [256][8192]  (fused transpose epi)
//   k2: gemm_ay        P[ks] = A_slice @ Y_slice, Rp[ks] = partial rowsum|A|
//   k3: finalize       Out = (sum_s P[s]) / max(sum_s Rp[s],eps) + bias
// ws: WT 256K | YT 4M | P 32M | Rp 128K = 36.4 MiB (atomic fallback: 12.9 MiB)

typedef __attribute__((ext_vector_type(8))) __bf16 bf16x8;
typedef __attribute__((ext_vector_type(4))) float f32x4;

#define AS1 __attribute__((address_space(1)))
#define AS3 __attribute__((address_space(3)))

__device__ __forceinline__ void async_load16(const void* g, void* l) {
  __builtin_amdgcn_global_load_lds((const AS1 void*)g, (AS3 void*)l, 16, 0, 0);
}

// ---------------- kernel: 64x64 tiled transpose + f32->bf16 ----------------
__global__ __launch_bounds__(256) void transpose_cvt_kernel(
    const float* __restrict__ src, __hip_bfloat16* __restrict__ dst, int R, int C) {
  __shared__ float tile[64][65];
  const int t = threadIdx.x;
  const int nrb = R >> 6;
  const int rb = blockIdx.x % nrb, cb = blockIdx.x / nrb;
  const int r0 = rb * 64, c0 = cb * 64;
  const int lr = t >> 4, lc4 = (t & 15) * 4;
#pragma unroll
  for (int p = 0; p < 4; ++p) {
    const int r = p * 16 + lr;
    const f32x4 v = *(const f32x4*)(src + (size_t)(r0 + r) * C + c0 + lc4);
    tile[r][lc4 + 0] = v[0]; tile[r][lc4 + 1] = v[1];
    tile[r][lc4 + 2] = v[2]; tile[r][lc4 + 3] = v[3];
  }
  __syncthreads();
#pragma unroll
  for (int i = 0; i < 16; ++i) {
    const int idx = i * 256 + t;
    const int n = idx >> 6, k = idx & 63;
    dst[(size_t)(c0 + n) * R + r0 + k] = __float2bfloat16(tile[k][n]);
  }
}

// ---------------- kernel: YT = (X @ W)^T  (small GEMM + fused transpose) ----------------
// BM=64, BN=128, BK=64, 256 threads (4 waves 2x2), wave-tile 32x64, 8 K-iters.
__global__ __launch_bounds__(256) void gemm_xw_kernel(
    const float* __restrict__ X,            // [8192][512] f32
    const __hip_bfloat16* __restrict__ WT,  // [256][512]
    __hip_bfloat16* __restrict__ YT)        // [256][8192] bf16
{
  __shared__ char smem[49152];
  char* Sbase = smem;            // [2][64 rows][128 B], chunk P = c ^ (row&7)
  char* Wbase = smem + 16384;    // [2][128 n  ][128 B], chunk P = c ^ (n&7)

  const int t = threadIdx.x;
  const int wave = t >> 6, lane = t & 63;
  const int quad = lane >> 4, l16 = lane & 15;

  const int b = blockIdx.x;
  const int xcd = b & 7, s = b >> 3;
  const int rb = xcd * 16 + (s >> 1), cb = s & 1;
  const int r0 = rb * 64, c0 = cb * 128;

  const int wm = wave & 1, wn = wave >> 1;

  f32x4 acc[2][4] = {};

  const int am = t >> 2;
  const int kq = t & 3;
  const float* sp = X + (size_t)(r0 + am) * 512 + kq * 16;
  const int sw0 = am * 128 + (((kq * 2 + 0) ^ (am & 7)) * 16);
  const int sw1 = am * 128 + (((kq * 2 + 1) ^ (am & 7)) * 16);

  f32x4 sreg[4];
#pragma unroll
  for (int i = 0; i < 4; ++i) sreg[i] = *(const f32x4*)(sp + i * 4);

  // W prologue (kt=0 -> buf0)
#pragma unroll
  for (int i = 0; i < 4; ++i) {
    const int slot = i * 256 + t;
    const int n = slot >> 3;
    const int G = (slot & 7) ^ (n & 7);
    async_load16(WT + (size_t)(c0 + n) * 512 + G * 8, Wbase + slot * 16);
  }

  int cur = 0;
#pragma unroll 2
  for (int kt = 0; kt < 8; ++kt) {
    {  // stage X(kt): cvt, 2 swizzled ds_write_b128
      char* sw = Sbase + cur * 8192;
      bf16x8 v0, v1;
#pragma unroll
      for (int j = 0; j < 4; ++j) {
        v0[j]     = (__bf16)(sreg[0][j]);
        v0[j + 4] = (__bf16)(sreg[1][j]);
        v1[j]     = (__bf16)(sreg[2][j]);
        v1[j + 4] = (__bf16)(sreg[3][j]);
      }
      *(bf16x8*)(sw + sw0) = v0;
      *(bf16x8*)(sw + sw1) = v1;
    }
    __syncthreads();

    if (kt < 7) {  // prefetch kt+1
      const float* spk = sp + (kt + 1) * 64;
#pragma unroll
      for (int i = 0; i < 4; ++i) sreg[i] = *(const f32x4*)(spk + i * 4);
#pragma unroll
      for (int i = 0; i < 4; ++i) {
        const int slot = i * 256 + t;
        const int n = slot >> 3;
        const int G = (slot & 7) ^ (n & 7);
        async_load16(WT + (size_t)(c0 + n) * 512 + (kt + 1) * 64 + G * 8,
                     Wbase + (cur ^ 1) * 16384 + slot * 16);
      }
    }

    {  // compute: 12 ds_read_b128 + 16 MFMA per wave
      const char* sb = Sbase + cur * 8192;
      const char* wb = Wbase + cur * 16384;
      bf16x8 af[2][2];
#pragma unroll
      for (int rt = 0; rt < 2; ++rt) {
        const int row = wm * 32 + rt * 16 + l16;
#pragma unroll
        for (int kb = 0; kb < 2; ++kb) {
          const int ch = (kb * 4 + quad) ^ (row & 7);
          af[rt][kb] = *(const bf16x8*)(sb + row * 128 + ch * 16);
        }
      }
#pragma unroll
      for (int ct = 0; ct < 4; ++ct) {
        const int n = wn * 64 + ct * 16 + l16;
#pragma unroll
        for (int kb = 0; kb < 2; ++kb) {
          const int ch = (kb * 4 + quad) ^ (n & 7);
          const bf16x8 bfr = *(const bf16x8*)(wb + n * 128 + ch * 16);
#pragma unroll
          for (int rt = 0; rt < 2; ++rt)
            acc[rt][ct] = __builtin_amdgcn_mfma_f32_16x16x32_bf16(
                af[rt][kb], bfr, acc[rt][ct], 0, 0, 0);
        }
      }
    }
    cur ^= 1;
  }

  // fused transpose epilogue: acc -> Tr[128 col][64 row] bf16 -> coalesced YT
  __syncthreads();  // all compute(7) reads done before Tr overwrites smem
  __hip_bfloat16* Tr = (__hip_bfloat16*)smem;  // 16 KiB
#pragma unroll
  for (int rt = 0; rt < 2; ++rt) {
#pragma unroll
    for (int r = 0; r < 4; ++r) {
      const int row_l = wm * 32 + rt * 16 + quad * 4 + r;   // C/D: row=(lane>>4)*4+reg
#pragma unroll
      for (int ct = 0; ct < 4; ++ct) {
        const int col_l = wn * 64 + ct * 16 + l16;          // C/D: col=lane&15
        Tr[col_l * 64 + row_l] = __float2bfloat16(acc[rt][ct][r]);
      }
    }
  }
  __syncthreads();
  // 128 cols x 64 rows x 2 B = 16 KiB = 1024 chunks of 16 B; 4 chunks/thread
#pragma unroll
  for (int i = 0; i < 4; ++i) {
    const int c = i * 256 + t;
    const int col = c >> 3, part = c & 7;
    *(f32x4*)(YT + (size_t)(c0 + col) * 8192 + r0 + part * 8) =
        *(const f32x4*)(Tr + col * 64 + part * 8);
  }
}

// ---------------- kernel: split-K  P[ks] = A_slice @ Y_slice ----------------
// BM=128, BN=256 (full width), BK=64, Kslice=2048 -> 32 iters, rotated order.
// grid 256 = 64 rb x 4 ks (ks = b&3 -> XCD pair, 1 MB Y slice L2-resident).
// 512 thr (8 waves 2x4, wave-tile 64x64). LDS 96 KiB: A [2][128][128B],
// Y [2][256][128B], chunk XOR-8 swizzle. Epilogue rowsum: in-wave shuffle
// (4 adjacent lanes per row), ZERO epilogue LDS use (R9 race fix).
__global__ __launch_bounds__(512, 2) void gemm_ay_kernel(
    const float* __restrict__ A,            // [8192][8192]
    const __hip_bfloat16* __restrict__ YT,  // [256][8192]
    float* __restrict__ Pb,                 // [4][8192][256] f32 (plain) or [8192][256] (atomic)
    float* __restrict__ Rb,                 // [4][8192] (plain) or [8192] (atomic, zeroed)
    int atomic_flag)
{
  __shared__ char smem[98304];
  char* Abase = smem;            // [2][128 rows][128 B]  2 x 16 KiB
  char* Ybase = smem + 32768;    // [2][256 n  ][128 B]  2 x 32 KiB

  const int t = threadIdx.x;
  const int wave = t >> 6, lane = t & 63;
  const int quad = lane >> 4, l16 = lane & 15;

  const int b = blockIdx.x;
  const int ks = b & 3;                      // K-slice, pinned to XCD pair
  const int rb = b >> 2;                     // 0..63
  const int r0 = rb * 128;
  const int k0 = ks * 2048;
  const int phase = (rb * 37) & 31;          // per-block K rotation (R8 win)

  const int wm = wave & 1, wn = wave >> 1;   // 2 x 4 waves, wave-tile 64x64

  f32x4 acc[4][4] = {};
  float rs = 0.0f;

  // A staging: thread -> row am = t>>2 (128 rows), 16-float group kq = t&3
  const int am = t >> 2, kq = t & 3;
  const float* ap = A + (size_t)(r0 + am) * 8192 + k0 + kq * 16;
  // swizzled write offsets for the two 16-B bf16 chunks (chunks 2kq, 2kq+1)
  const int aw0 = am * 128 + (((2 * kq + 0) ^ (am & 7)) * 16);
  const int aw1 = am * 128 + (((2 * kq + 1) ^ (am & 7)) * 16);

  f32x4 areg[2][4];
  // prologue: A(phase) -> areg[0], A(phase+1) -> areg[1], Y(phase) -> Ybuf0
  {
    const int kk0 = phase, kk1 = (phase + 1) & 31;
#pragma unroll
    for (int i = 0; i < 4; ++i) areg[0][i] = *(const f32x4*)(ap + kk0 * 64 + i * 4);
#pragma unroll
    for (int i = 0; i < 4; ++i) areg[1][i] = *(const f32x4*)(ap + kk1 * 64 + i * 4);
#pragma unroll
    for (int i = 0; i < 4; ++i) {
      const int s = i * 512 + t;             // 2048 slots of 16 B
      const int n = s >> 3;
      const int G = (s & 7) ^ (n & 7);
      async_load16(YT + (size_t)n * 8192 + k0 + kk0 * 64 + G * 8, Ybase + s * 16);
    }
  }

  int cur = 0;
#pragma unroll 2
  for (int kt = 0; kt < 32; ++kt) {
    {  // stage A(kt): rowsum + cvt + 2 swizzled ds_write_b128
      const int p = kt & 1;
      const f32x4 a0 = areg[p][0], a1 = areg[p][1], a2 = areg[p][2], a3 = areg[p][3];
      rs += fabsf(a0[0]) + fabsf(a0[1]) + fabsf(a0[2]) + fabsf(a0[3]) +
            fabsf(a1[0]) + fabsf(a1[1]) + fabsf(a1[2]) + fabsf(a1[3]) +
            fabsf(a2[0]) + fabsf(a2[1]) + fabsf(a2[2]) + fabsf(a2[3]) +
            fabsf(a3[0]) + fabsf(a3[1]) + fabsf(a3[2]) + fabsf(a3[3]);
      bf16x8 v0, v1;
#pragma unroll
      for (int j = 0; j < 4; ++j) {
        v0[j] = (__bf16)a0[j]; v0[j + 4] = (__bf16)a1[j];
        v1[j] = (__bf16)a2[j]; v1[j + 4] = (__bf16)a3[j];
      }
      char* aw = Abase + cur * 16384;
      *(bf16x8*)(aw + aw0) = v0;
      *(bf16x8*)(aw + aw1) = v1;
    }
    __syncthreads();

    if (kt < 30) {  // depth-2 A prefetch: column (kt+2+phase)&31 -> areg[kt&1]
      const int kk2 = (kt + 2 + phase) & 31;
      const float* apk = ap + (size_t)kk2 * 64;
#pragma unroll
      for (int i = 0; i < 4; ++i) areg[kt & 1][i] = *(const f32x4*)(apk + i * 4);
    }
    if (kt < 31) {  // Y column (kt+1+phase)&31 -> Ybuf^1 (L2-resident stream)
      const int kk1 = (kt + 1 + phase) & 31;
#pragma unroll
      for (int i = 0; i < 4; ++i) {
        const int s = i * 512 + t;
        const int n = s >> 3;
        const int G = (s & 7) ^ (n & 7);
        async_load16(YT + (size_t)n * 8192 + k0 + kk1 * 64 + G * 8,
                     Ybase + (cur ^ 1) * 32768 + s * 16);
      }
    }

    {  // compute: 16 ds_read_b128 + 32 MFMA per wave
      const char* ab = Abase + cur * 16384;
      const char* yb = Ybase + cur * 32768;
      bf16x8 af[4][2];
#pragma unroll
      for (int rt = 0; rt < 4; ++rt) {
        const int row = wm * 64 + rt * 16 + l16;
#pragma unroll
        for (int kb = 0; kb < 2; ++kb) {
          const int ch = (kb * 4 + quad) ^ (row & 7);
          af[rt][kb] = *(const bf16x8*)(ab + row * 128 + ch * 16);
        }
      }
#pragma unroll
      for (int ct = 0; ct < 4; ++ct) {
        const int n = wn * 64 + ct * 16 + l16;
#pragma unroll
        for (int kb = 0; kb < 2; ++kb) {
          const int ch = (kb * 4 + quad) ^ (n & 7);
          const bf16x8 bfr = *(const bf16x8*)(yb + n * 128 + ch * 16);
#pragma unroll
          for (int rt = 0; rt < 4; ++rt)
            acc[rt][ct] = __builtin_amdgcn_mfma_f32_16x16x32_bf16(
                af[rt][kb], bfr, acc[rt][ct], 0, 0, 0);
        }
      }
    }
    cur ^= 1;
  }

  // epilogue: rowsum via in-wave shuffle. Row am = t>>2 is held by 4 ADJACENT
  // lanes of one wave (4-aligned groups never cross the 64-lane boundary).
  // No LDS, no barrier -> no aliasing with in-flight compute(31) reads.
  rs += __shfl_xor(rs, 1);
  rs += __shfl_xor(rs, 2);
  if ((t & 3) == 0) {
    const int row = t >> 2;  // == am
    if (atomic_flag) atomicAdd(&Rb[r0 + row], rs);
    else             Rb[(size_t)ks * 8192 + r0 + row] = rs;
  }

  if (atomic_flag) {
#pragma unroll
    for (int rt = 0; rt < 4; ++rt)
#pragma unroll
      for (int r = 0; r < 4; ++r) {
        const int row_l = wm * 64 + rt * 16 + quad * 4 + r;  // C/D: row=(lane>>4)*4+reg
#pragma unroll
        for (int ct = 0; ct < 4; ++ct) {
          const int col_l = wn * 64 + ct * 16 + l16;         // C/D: col=lane&15
          atomicAdd(&Pb[(size_t)(r0 + row_l) * 256 + col_l], acc[rt][ct][r]);
        }
      }
  } else {
    float* dst = Pb + (size_t)ks * (8192 * 256);
#pragma unroll
    for (int rt = 0; rt < 4; ++rt)
#pragma unroll
      for (int r = 0; r < 4; ++r) {
        const int row_l = wm * 64 + rt * 16 + quad * 4 + r;
#pragma unroll
        for (int ct = 0; ct < 4; ++ct) {
          const int col_l = wn * 64 + ct * 16 + l16;
          dst[(size_t)(r0 + row_l) * 256 + col_l] = acc[rt][ct][r];
        }
      }
  }
}

// ---------------- kernel: Out = (sum_s P[s]) / max(sum_s Rp[s], eps) + bias ----------------
__global__ __launch_bounds__(256) void finalize_kernel(
    const float* __restrict__ Pb,   // [S][8192][256]
    const float* __restrict__ Rb,   // [S][8192]
    const float* __restrict__ bias, // [256]
    float* __restrict__ Out,        // [8192][256]
    int S)
{
  const int idx = blockIdx.x * 256 + threadIdx.x;
  const int i  = idx >> 6;          // row
  const int j4 = (idx & 63) << 2;   // col (x4)
  float rsum = 0.0f;
  for (int s = 0; s < S; ++s) rsum += Rb[(size_t)s * 8192 + i];
  const float inv = 1.0f / fmaxf(rsum, 1e-12f);
  f32x4 a = {};
  for (int s = 0; s < S; ++s) {
    const f32x4 p = *(const f32x4*)(Pb + (size_t)s * (8192 * 256) + (size_t)i * 256 + j4);
    a += p;
  }
  const f32x4 bv = *(const f32x4*)(bias + j4);
  const f32x4 o = a * inv + bv;
  *(f32x4*)(Out + (size_t)i * 256 + j4) = o;
}

extern "C" void kernel_launch(void* const* d_in, const int* in_sizes, int n_in,
                              void* d_out, int out_size, void* d_ws, size_t ws_size,
                              hipStream_t stream) {
  const float* A    = (const float*)d_in[0];
  const float* Xf   = (const float*)d_in[1];
  const float* Wf   = (const float*)d_in[2];
  const float* bias = (const float*)d_in[3];
  float* Out = (float*)d_out;

  char* ws = (char*)d_ws;
  __hip_bfloat16* WT = (__hip_bfloat16*)ws;                 // [256][512]   256 KiB
  __hip_bfloat16* YT = (__hip_bfloat16*)(ws + 262144);      // [256][8192]  4 MiB
  char*         tail = ws + 4456448;

  const size_t need_plain = 4456448ull + 33554432ull + 131072ull;  // +P(32M)+Rp(128K)
  float* Pb; float* Rb; int atomic_flag; int S;
  if (ws_size >= need_plain) {
    Pb = (float*)tail;                     // [4][8192][256] 32 MiB
    Rb = (float*)(tail + 33554432);        // [4][8192]      128 KiB
    atomic_flag = 0; S = 4;
  } else {
    Pb = (float*)tail;                     // [8192][256]    8 MiB
    Rb = (float*)(tail + 8388608);         // [8192]         32 KiB
    atomic_flag = 1; S = 1;
    hipMemsetAsync(tail, 0, 8388608 + 32768, stream);
  }

  transpose_cvt_kernel<<<32, 256, 0, stream>>>(Wf, WT, 512, 256);
  gemm_xw_kernel<<<256, 256, 0, stream>>>(Xf, WT, YT);
  gemm_ay_kernel<<<256, 512, 0, stream>>>(A, YT, Pb, Rb, atomic_flag);
  finalize_kernel<<<2048, 256, 0, stream>>>(Pb, Rb, bias, Out, S);
}